// Round 18
// baseline (155.013 us; speedup 1.0000x reference)
//
#include <hip/hip_runtime.h>

#define BATCH 262144

typedef __attribute__((ext_vector_type(8))) short short8;
typedef __attribute__((ext_vector_type(4))) float f32x4;

static __device__ __forceinline__ unsigned cvtpk(float lo, float hi) {
    unsigned r;
    asm("v_cvt_pk_bf16_f32 %0, %1, %2" : "=v"(r) : "v"(lo), "v"(hi));
    return r;
}
// float -> bf16 bits (RNE) for the weight-prep kernel
static __device__ __forceinline__ unsigned short f2b(float f) {
    unsigned u = __float_as_uint(f);
    return (unsigned short)((u + 0x7fffu + ((u >> 16) & 1u)) >> 16);
}
static __device__ __forceinline__ float sigm(float x) { return 1.0f / (1.0f + __expf(-x)); }
static __device__ __forceinline__ float tanh_f(float x) { return 1.0f - 2.0f / (__expf(2.0f * x) + 1.0f); }

// LDS serves a wave's DS ops in program order; compiler-only barrier keeps
// instruction order (R15: verified correct, neutral vs lgkmcnt(0) drain).
#define WAVE_FENCE() asm volatile("" ::: "memory")

// XOR swizzle on 16B slots within a row (R4/R10-validated, <=2-way aliasing).
static __device__ __forceinline__ int sw128(int row, int cb) { return row * 128 + (cb ^ ((row & 7) << 4)); }
static __device__ __forceinline__ int sw256(int row, int cb) { return row * 256 + (cb ^ ((row & 7) << 4)); }

// bf16 weights flat in workspace (bytes): w1[0,16384) w2[16384,24576)
// wih[24576,49152) whh[49152,73728) lw1[73728,90112)
__global__ void prep_weights(const float* __restrict__ w1, const float* __restrict__ w2,
                             const float* __restrict__ wih, const float* __restrict__ whh,
                             const float* __restrict__ lw1, unsigned short* __restrict__ wsb) {
    int i = blockIdx.x * 256 + threadIdx.x;
    float v;
    if (i < 8192) v = w1[i];
    else if (i < 12288) v = w2[i - 8192];
    else if (i < 24576) v = wih[i - 12288];
    else if (i < 36864) v = whh[i - 24576];
    else if (i < 45056) v = lw1[i - 36864];
    else return;
    wsb[i] = f2b(v);
}

// Weight LDS (swizzled): w1 @0 [64][128]s256, w2 @16384 [64][64]s128,
// wih @24576 [192][64]s128, whh @49152 [192][64]s128, lw1 @73728 [64][128]s256
#define WLDS_BYTES 90112
#define NCHUNK (WLDS_BYTES / 16)

// R18: 1024 threads = 16 waves; per-wave LDS cut 6KB -> 4KB by time-sharing
// two 2KB buffers (buf0: n1->h1->c1, buf1: n2->msg->c2). Enabled by:
//  - x1/x2 A-fragments loaded ONCE in stage 1 (regs, live through stage 3)
//  - GRU h read from GLOBAL f32 (persistent blocks => rows still L2-hot;
//    R6's regression came from 512 transient blocks evicting L2)
// LDS 90112 + 16*4096 = 155648 B -> 1 block/CU, 4 waves/SIMD (+33% vs R15).
// Reg budget at 1024 thr = 128/wave; body est. ~100. WRITE_SIZE is the tell.
__global__ __launch_bounds__(1024) void tgn_kernel(
    const int* __restrict__ pairs, const float* __restrict__ memory,
    const unsigned short* __restrict__ wsb,
    const float* __restrict__ b1, const float* __restrict__ b2,
    const float* __restrict__ bih, const float* __restrict__ bhh,
    const float* __restrict__ lb1, const float* __restrict__ lw2,
    const float* __restrict__ lb2, float* __restrict__ out)
{
    __shared__ __align__(16) char wlds[WLDS_BYTES];  // all 5 weight tiles, swizzled
    __shared__ __align__(16) char work[16][4096];    // per-wave: buf0(2K) buf1(2K)

    const int tid = threadIdx.x;
    const int w  = tid >> 6;
    const int l  = tid & 63;
    const int lr = l & 15;       // M/N index within fragment
    const int lg = l >> 4;       // k-group / row-group

    // ---- stage weights once: global (flat) -> LDS (swizzled), 16B chunks ----
    for (int c = tid; c < NCHUNK; c += 1024) {
        int byte = c * 16;
        int base, sh;
        if (byte < 16384)      { base = 0;     sh = 8; }   // w1, 256B rows
        else if (byte < 24576) { base = 16384; sh = 7; }   // w2, 128B rows
        else if (byte < 49152) { base = 24576; sh = 7; }   // wih
        else if (byte < 73728) { base = 49152; sh = 7; }   // whh
        else                   { base = 73728; sh = 8; }   // lw1
        int t   = byte - base;
        int row = t >> sh;
        int dst = base + (t ^ ((row & 7) << 4));
        *(short8*)(wlds + dst) = *(const short8*)((const char*)wsb + byte);
    }
    __syncthreads();   // weights visible to all waves (only block barrier)

    char* buf0 = &work[w][0];     // n1 -> h1 -> c1   ([16][64] bf16 sw128)
    char* buf1 = &work[w][2048];  // n2 -> msg -> c2

    const char* w1l  = wlds + 0;      // [64][128] s256
    const char* w2l  = wlds + 16384;  // [64][64]  s128
    const char* wihl = wlds + 24576;  // [192][64] s128
    const char* whhl = wlds + 49152;  // [192][64] s128
    const char* lw1l = wlds + 73728;  // [64][128] s256

    const f32x4 z4 = {0.0f, 0.0f, 0.0f, 0.0f};

    const int waveid = blockIdx.x * 16 + w;   // 0..4095; 4 tiles each, exact

    // gather-pairs prefetch: 4x int2 = 8 VGPRs (rows rr*4+lg of current tile)
    int2 pr[4];
#pragma unroll
    for (int rr = 0; rr < 4; ++rr)
        pr[rr] = *(const int2*)(pairs + (waveid * 16 + rr * 4 + lg) * 2);

#pragma unroll 1   // one body copy: I$-hot across iterations
    for (int tile = waveid; tile < 16384; tile += 4096) {
        const int r0 = tile * 16;

        // ---- stage 0: gather rows (pairs resident) -> bf16 LDS ----
#pragma unroll
        for (int rr = 0; rr < 4; ++rr) {
            int row = rr * 4 + lg;
            f32x4 v1 = *(const f32x4*)(memory + (long)pr[rr].x * 64 + lr * 4);
            f32x4 v2 = *(const f32x4*)(memory + (long)pr[rr].y * 64 + lr * 4);
            uint2 c1v, c2v;
            c1v.x = cvtpk(v1[0], v1[1]); c1v.y = cvtpk(v1[2], v1[3]);
            c2v.x = cvtpk(v2[0], v2[1]); c2v.y = cvtpk(v2[2], v2[3]);
            int off = sw128(row, lr * 8);
            *(uint2*)(buf0 + off) = c1v;
            *(uint2*)(buf1 + off) = c2v;
        }
        // h-pairs for GRU (rows lg*4+r of CURRENT tile); L1-hot broadcast reads
        int2 hpr[4];
#pragma unroll
        for (int r = 0; r < 4; ++r)
            hpr[r] = *(const int2*)(pairs + (r0 + lg * 4 + r) * 2);
        // prefetch next tile's gather pairs
        {
            int next = tile + 4096;
            if (next < 16384) {
#pragma unroll
                for (int rr = 0; rr < 4; ++rr)
                    pr[rr] = *(const int2*)(pairs + (next * 16 + rr * 4 + lg) * 2);
            }
        }
        WAVE_FENCE();

        // ---- stage 1: x1/x2 A-frags ONCE (live through stage 3), then
        //      H1 = relu(X @ w1^T + b1); h1 overwrites buf0 (n1 consumed) ----
        short8 x1[2], x2[2];
#pragma unroll
        for (int kt = 0; kt < 2; ++kt) {
            x1[kt] = *(const short8*)(buf0 + sw128(lr, kt * 64 + lg * 16));
            x2[kt] = *(const short8*)(buf1 + sw128(lr, kt * 64 + lg * 16));
        }
        WAVE_FENCE();
        f32x4 acc[4];
#pragma unroll
        for (int nt = 0; nt < 4; ++nt) acc[nt] = z4;
#pragma unroll
        for (int kt = 0; kt < 4; ++kt) {
            short8 a = (kt == 0) ? x1[0] : (kt == 1) ? x1[1] : (kt == 2) ? x2[0] : x2[1];
#pragma unroll
            for (int nt = 0; nt < 4; ++nt) {
                short8 b = *(const short8*)(w1l + sw256(nt * 16 + lr, kt * 64 + lg * 16));
                acc[nt] = __builtin_amdgcn_mfma_f32_16x16x32_bf16(a, b, acc[nt], 0, 0, 0);
            }
        }
#pragma unroll
        for (int nt = 0; nt < 4; ++nt) {
            float bv = b1[nt * 16 + lr];
            unsigned p01 = cvtpk(fmaxf(acc[nt][0] + bv, 0.0f), fmaxf(acc[nt][1] + bv, 0.0f));
            unsigned p23 = cvtpk(fmaxf(acc[nt][2] + bv, 0.0f), fmaxf(acc[nt][3] + bv, 0.0f));
            int cb = nt * 32 + lr * 2;
            *(short*)(buf0 + sw128(lg * 4 + 0, cb)) = (short)p01;
            *(short*)(buf0 + sw128(lg * 4 + 1, cb)) = (short)(p01 >> 16);
            *(short*)(buf0 + sw128(lg * 4 + 2, cb)) = (short)p23;
            *(short*)(buf0 + sw128(lg * 4 + 3, cb)) = (short)(p23 >> 16);
        }
        WAVE_FENCE();

        // ---- stage 2: MSG = H1 @ w2^T + b2; msg overwrites buf1 (n2 consumed) ----
#pragma unroll
        for (int nt = 0; nt < 4; ++nt) acc[nt] = z4;
#pragma unroll
        for (int kt = 0; kt < 2; ++kt) {
            short8 a = *(const short8*)(buf0 + sw128(lr, kt * 64 + lg * 16));
#pragma unroll
            for (int nt = 0; nt < 4; ++nt) {
                short8 b = *(const short8*)(w2l + sw128(nt * 16 + lr, kt * 64 + lg * 16));
                acc[nt] = __builtin_amdgcn_mfma_f32_16x16x32_bf16(a, b, acc[nt], 0, 0, 0);
            }
        }
#pragma unroll
        for (int nt = 0; nt < 4; ++nt) {
            float bv = b2[nt * 16 + lr];
            unsigned p01 = cvtpk(acc[nt][0] + bv, acc[nt][1] + bv);
            unsigned p23 = cvtpk(acc[nt][2] + bv, acc[nt][3] + bv);
            int cb = nt * 32 + lr * 2;
            *(short*)(buf1 + sw128(lg * 4 + 0, cb)) = (short)p01;
            *(short*)(buf1 + sw128(lg * 4 + 1, cb)) = (short)(p01 >> 16);
            *(short*)(buf1 + sw128(lg * 4 + 2, cb)) = (short)p23;
            *(short*)(buf1 + sw128(lg * 4 + 3, cb)) = (short)(p23 >> 16);
        }
        WAVE_FENCE();

        // ---- stage 3+4: am from buf1(msg); gates; GRU with h from GLOBAL f32;
        //      comb overwrites buf0 (c1) and buf1 (c2) ----
        short8 am[2];
        am[0] = *(const short8*)(buf1 + sw128(lr, lg * 16));
        am[1] = *(const short8*)(buf1 + sw128(lr, 64 + lg * 16));
        WAVE_FENCE();
#pragma unroll
        for (int nt = 0; nt < 4; ++nt) {
            f32x4 gir = z4, giz = z4, gin = z4;
            f32x4 g1r = z4, g1z = z4, g1n = z4;
            f32x4 g2r = z4, g2z = z4, g2n = z4;
#pragma unroll
            for (int kt = 0; kt < 2; ++kt) {
                int ko = kt * 64 + lg * 16;
                short8 bir = *(const short8*)(wihl + sw128((0 + nt) * 16 + lr, ko));
                short8 biz = *(const short8*)(wihl + sw128((4 + nt) * 16 + lr, ko));
                short8 bin = *(const short8*)(wihl + sw128((8 + nt) * 16 + lr, ko));
                short8 bhr = *(const short8*)(whhl + sw128((0 + nt) * 16 + lr, ko));
                short8 bhz = *(const short8*)(whhl + sw128((4 + nt) * 16 + lr, ko));
                short8 bhn = *(const short8*)(whhl + sw128((8 + nt) * 16 + lr, ko));
                short8 a1k = x1[kt], a2k = x2[kt];
                gir = __builtin_amdgcn_mfma_f32_16x16x32_bf16(am[kt], bir, gir, 0, 0, 0);
                giz = __builtin_amdgcn_mfma_f32_16x16x32_bf16(am[kt], biz, giz, 0, 0, 0);
                gin = __builtin_amdgcn_mfma_f32_16x16x32_bf16(am[kt], bin, gin, 0, 0, 0);
                g1r = __builtin_amdgcn_mfma_f32_16x16x32_bf16(a1k, bhr, g1r, 0, 0, 0);
                g1z = __builtin_amdgcn_mfma_f32_16x16x32_bf16(a1k, bhz, g1z, 0, 0, 0);
                g1n = __builtin_amdgcn_mfma_f32_16x16x32_bf16(a1k, bhn, g1n, 0, 0, 0);
                g2r = __builtin_amdgcn_mfma_f32_16x16x32_bf16(a2k, bhr, g2r, 0, 0, 0);
                g2z = __builtin_amdgcn_mfma_f32_16x16x32_bf16(a2k, bhz, g2z, 0, 0, 0);
                g2n = __builtin_amdgcn_mfma_f32_16x16x32_bf16(a2k, bhn, g2n, 0, 0, 0);
            }
            int j = nt * 16 + lr;
            float bir_ = bih[j], biz_ = bih[64 + j], bin_ = bih[128 + j];
            float bhr_ = bhh[j], bhz_ = bhh[64 + j], bhn_ = bhh[128 + j];
            float o1[4], o2[4];
#pragma unroll
            for (int r = 0; r < 4; ++r) {
                float i_r = gir[r] + bir_;
                float i_z = giz[r] + biz_;
                float i_n = gin[r] + bin_;
                // h from global f32 (L2-hot: same rows touched ~2-3K cyc ago)
                float h1v = memory[(long)hpr[r].x * 64 + j];
                float h2v = memory[(long)hpr[r].y * 64 + j];
                float rg = sigm(i_r + g1r[r] + bhr_);
                float zg = sigm(i_z + g1z[r] + bhz_);
                float ng = tanh_f(i_n + rg * (g1n[r] + bhn_));
                o1[r] = (1.0f - zg) * ng + zg * h1v;
                rg = sigm(i_r + g2r[r] + bhr_);
                zg = sigm(i_z + g2z[r] + bhz_);
                ng = tanh_f(i_n + rg * (g2n[r] + bhn_));
                o2[r] = (1.0f - zg) * ng + zg * h2v;
            }
            unsigned q01 = cvtpk(o1[0], o1[1]), q23 = cvtpk(o1[2], o1[3]);
            unsigned s01 = cvtpk(o2[0], o2[1]), s23 = cvtpk(o2[2], o2[3]);
            *(short*)(buf0 + sw128(lg * 4 + 0, j * 2)) = (short)q01;
            *(short*)(buf0 + sw128(lg * 4 + 1, j * 2)) = (short)(q01 >> 16);
            *(short*)(buf0 + sw128(lg * 4 + 2, j * 2)) = (short)q23;
            *(short*)(buf0 + sw128(lg * 4 + 3, j * 2)) = (short)(q23 >> 16);
            *(short*)(buf1 + sw128(lg * 4 + 0, j * 2)) = (short)s01;
            *(short*)(buf1 + sw128(lg * 4 + 1, j * 2)) = (short)(s01 >> 16);
            *(short*)(buf1 + sw128(lg * 4 + 2, j * 2)) = (short)s23;
            *(short*)(buf1 + sw128(lg * 4 + 3, j * 2)) = (short)(s23 >> 16);
        }
        WAVE_FENCE();

        // ---- stage 5: H = relu(COMB @ lp_w1^T + lb1); comb = [c1|c2] ----
        f32x4 acc5[4];
#pragma unroll
        for (int nt = 0; nt < 4; ++nt) acc5[nt] = z4;
#pragma unroll
        for (int kt = 0; kt < 4; ++kt) {
            const char* base = (kt < 2) ? buf0 : buf1;
            short8 a = *(const short8*)(base + sw128(lr, (kt & 1) * 64 + lg * 16));
#pragma unroll
            for (int nt = 0; nt < 4; ++nt) {
                short8 b = *(const short8*)(lw1l + sw256(nt * 16 + lr, kt * 64 + lg * 16));
                acc5[nt] = __builtin_amdgcn_mfma_f32_16x16x32_bf16(a, b, acc5[nt], 0, 0, 0);
            }
        }

        // ---- stage 6: out = sigmoid(H @ lp_w2^T + lb2), reduce over 64 cols ----
        float part[4] = {0.0f, 0.0f, 0.0f, 0.0f};
#pragma unroll
        for (int nt = 0; nt < 4; ++nt) {
            float w2v = lw2[nt * 16 + lr];
            float bv  = lb1[nt * 16 + lr];
#pragma unroll
            for (int r = 0; r < 4; ++r)
                part[r] += fmaxf(acc5[nt][r] + bv, 0.0f) * w2v;
        }
        float lb2v = lb2[0];
#pragma unroll
        for (int r = 0; r < 4; ++r) {
            float p = part[r];
            p += __shfl_xor(p, 1);
            p += __shfl_xor(p, 2);
            p += __shfl_xor(p, 4);
            p += __shfl_xor(p, 8);
            if (lr == 0) out[r0 + lg * 4 + r] = sigm(p + lb2v);
        }
        // loop-top LDS writes are WAR-safe vs stage-5 reads: DS in-order per wave.
    }
}

extern "C" void kernel_launch(void* const* d_in, const int* in_sizes, int n_in,
                              void* d_out, int out_size, void* d_ws, size_t ws_size,
                              hipStream_t stream) {
    const int*   pairs  = (const int*)d_in[0];
    const float* memory = (const float*)d_in[1];
    const float* w1  = (const float*)d_in[2];
    const float* b1  = (const float*)d_in[3];
    const float* w2  = (const float*)d_in[4];
    const float* b2  = (const float*)d_in[5];
    const float* wih = (const float*)d_in[6];
    const float* whh = (const float*)d_in[7];
    const float* bih = (const float*)d_in[8];
    const float* bhh = (const float*)d_in[9];
    const float* lw1 = (const float*)d_in[10];
    const float* lb1 = (const float*)d_in[11];
    const float* lw2 = (const float*)d_in[12];
    const float* lb2 = (const float*)d_in[13];
    unsigned short* wsb = (unsigned short*)d_ws;

    prep_weights<<<176, 256, 0, stream>>>(w1, w2, wih, whh, lw1, wsb);
    // persistent: 256 blocks (1/CU), 16 waves each, 4 tiles per wave (exact)
    tgn_kernel<<<256, 1024, 0, stream>>>(pairs, memory, wsb, b1, b2, bih, bhh,
                                         lb1, lw2, lb2, (float*)d_out);
}